// Round 4
// baseline (104.650 us; speedup 1.0000x reference)
//
#include <hip/hip_runtime.h>
#include <hip/hip_cooperative_groups.h>
#include <math.h>

namespace cg = cooperative_groups;

#define NH   16
#define LCACHE 4096

typedef __attribute__((ext_vector_type(8))) short short8;
typedef __attribute__((ext_vector_type(8))) unsigned short ushort8;
typedef __attribute__((ext_vector_type(4))) float f32x4;

struct MegaArgs {
    const float *cached_k, *cached_v, *kcw, *vcw, *lkg, *lkb, *lvg, *lvb;
    const float *x, *w_attn, *b_attn, *w_proj, *b_proj;
    ushort *xp, *wq, *wp, *yp;
    float *out;
};

__device__ __forceinline__ unsigned short f2bf(float f) {
    unsigned int u = __float_as_uint(f);
    u = (u + 0x7fffu + ((u >> 16) & 1u)) >> 16;   // RNE
    return (unsigned short)u;
}
__device__ __forceinline__ void gload16(const ushort* g, ushort* l) {
    __builtin_amdgcn_global_load_lds((const __attribute__((address_space(1))) void*)g,
                                     (__attribute__((address_space(3))) void*)l, 16, 0, 0);
}

// stage one K-tile (A 4 frags + B 8 frags) into stg buffer `buf`
__device__ __forceinline__ void stage6(const ushort* agb, const ushort* bgb,
                                       ushort* stgb, int buf, int kt, int w4, int l)
{
    const ushort* ga = agb + (size_t)kt * 2048 + w4 * 512 + l * 8;
    const ushort* gb = bgb + (size_t)kt * 4096 + w4 * 1024 + l * 8;
    ushort* la = stgb + buf * 6144 + w4 * 512;
    ushort* lb = stgb + buf * 6144 + 2048 + w4 * 1024;
    gload16(ga, la); gload16(gb, lb); gload16(gb + 512, lb + 512);
}

// conv(stride4,k4)+LayerNorm for this block's (b,h,half) into LDS.
// wi: wave index within the compress group, nw: group size (4 fused / 8 fallback).
__device__ __forceinline__ void do_compress(const MegaArgs& a, int b, int h, int half,
                                            int wi, int nw, int l,
                                            float (*ck_s)[65], float (*cv_s)[65])
{
    const int NR = half ? 64 : 32;
    const int iters = (2 * NR) / nw;
    float4 wk = *(const float4*)(a.kcw + l * 4);
    float4 wv = *(const float4*)(a.vcw + l * 4);
    float gk = a.lkg[l], bk = a.lkb[l], gv = a.lvg[l], bv = a.lvb[l];
    const float* Kb = a.cached_k + (size_t)(b * NH + h) * (LCACHE * 64);
    const float* Vb = a.cached_v + (size_t)(b * NH + h) * (LCACHE * 64);

    for (int it = 0; it < iters; it += 4) {          // batch 4 rows: 8-way shuffle ILP
        float av[4]; int lcv[4], kk[4];
#pragma unroll
        for (int q = 0; q < 4; ++q) {
            int t  = wi + (it + q) * nw;
            kk[q]  = (t < NR);
            int lc = kk[q] ? t : t - NR;
            lcv[q] = lc;
            const float* src = (kk[q] ? Kb : Vb) + (size_t)lc * 256 + l;
            float4 cw = kk[q] ? wk : wv;
            float acc = src[0] * cw.x;
            acc = fmaf(src[64],  cw.y, acc);
            acc = fmaf(src[128], cw.z, acc);
            acc = fmaf(src[192], cw.w, acc);
            av[q] = acc;
        }
        float s1[4], s2[4];
#pragma unroll
        for (int q = 0; q < 4; ++q) { s1[q] = av[q]; s2[q] = av[q] * av[q]; }
#pragma unroll
        for (int o = 32; o; o >>= 1) {
#pragma unroll
            for (int q = 0; q < 4; ++q) {
                s1[q] += __shfl_xor(s1[q], o);
                s2[q] += __shfl_xor(s2[q], o);
            }
        }
#pragma unroll
        for (int q = 0; q < 4; ++q) {
            float mu  = s1[q] * 0.015625f;
            float var = s2[q] * 0.015625f - mu * mu;
            float g = kk[q] ? gk : gv, bb = kk[q] ? bk : bv;
            float outv = (av[q] - mu) * rsqrtf(var + 1e-5f) * g + bb;
            float (*dst)[65] = kk[q] ? ck_s : cv_s;
            dst[lcv[q]][l] = outv;
        }
    }
}

// pack x -> A frags, w_attn[:, :1024] -> wq frags, w_proj -> wp frags (bf16).
__device__ __forceinline__ void do_pack(const MegaArgs& a, int bid, int wi, int nw, int l)
{
    int r = l & 15, kg8 = l >> 4;
    for (int idx = wi; idx < 20; idx += nw) {
        int f = bid * 20 + idx;                  // 0..5119
        ushort8 o;
        if (f < 1024) {                          // A: x [512][1024]
            int mt = f >> 6, kt = (f >> 2) & 15, fi = f & 3;
            int kb = fi >> 1, mb = fi & 1;
            int m  = mt * 32 + mb * 16 + r;
            int k0 = kt * 64 + kb * 32 + kg8 * 8;
            const float* s = a.x + (size_t)m * 1024 + k0;
#pragma unroll
            for (int j = 0; j < 8; ++j) o[j] = f2bf(s[j]);
            *(ushort8*)(a.xp + (size_t)f * 512 + l * 8) = o;
        } else {                                 // B: w_attn / w_proj
            int g = f - 1024;
            const float* W; ushort* D; int ldw;
            if (g < 2048) { W = a.w_attn; D = a.wq; ldw = 3072; }
            else          { g -= 2048; W = a.w_proj; D = a.wp; ldw = 1024; }
            int nt = g >> 7, kt = (g >> 3) & 15, bi = g & 7;
            int kb = bi >> 2, nb = bi & 3;
            int k0 = kt * 64 + kb * 32 + kg8 * 8;
            int n  = nt * 64 + nb * 16 + r;
#pragma unroll
            for (int j = 0; j < 8; ++j) o[j] = f2bf(W[(size_t)(k0 + j) * ldw + n]);
            *(ushort8*)(D + (size_t)g * 512 + l * 8) = o;
        }
    }
}

// ---------------------------------------------------------------------------
// mode -1: fully fused (cooperative, grid.sync between phases)
// mode 0/1/2: fallback single-phase kernels (pack / compress+qgemm+attn / gemm2)
// ---------------------------------------------------------------------------
__global__ __launch_bounds__(512)
void mega_kernel(MegaArgs a, int mode)
{
    __shared__ __align__(16) ushort stg[2][3][6144];  // 73728 B
    __shared__ float ck_s[64][65];
    __shared__ float cv_s[64][65];
    __shared__ float qs[32][68];

    const bool fused = (mode < 0);
    const int bid = blockIdx.x;
    const int tid = threadIdx.x;
    const int w = tid >> 6, l = tid & 63;
    const int kg = w >> 2, w4 = w & 3;

    const int h    = ((bid & 7) << 1) | ((bid >> 3) & 1);  // same h -> same XCD
    const int rem  = bid >> 4;
    const int b    = rem >> 1;
    const int half = rem & 1;
    const int mtA  = b * 2 + half;

    // ---------------- phase 0: compress | pack (wave-specialized in fused mode)
    if ((fused || mode == 1) && !half) {
        // zero V rows 32..63 (avoid 0 * garbage-NaN in the PV loop)
#pragma unroll
        for (int t = 0; t < 4; ++t) cv_s[32 + w + t * 8][l] = 0.f;
    }
    if (fused) {
        if (w < 4) do_compress(a, b, h, half, w, 4, l, ck_s, cv_s);
        else       do_pack(a, bid, w - 4, 4, l);
    } else if (mode == 1) {
        do_compress(a, b, h, half, w, 8, l, ck_s, cv_s);
    } else if (mode == 0) {
        do_pack(a, bid, w, 8, l);
    }

    if (fused) cg::this_grid().sync();

    // ---------------- phase 1: qgemm (split-K pipeline) + attention
    if (fused || mode == 1) {
        const ushort* agb = a.xp + (size_t)mtA * 32768;
        const ushort* bgb = a.wq + (size_t)h * 65536;
        ushort* stgb = &stg[kg][0][0];
        stage6(agb, bgb, stgb, 0, kg * 8 + 0, w4, l);
        stage6(agb, bgb, stgb, 1, kg * 8 + 1, w4, l);

        f32x4 acc0 = {0.f,0.f,0.f,0.f}, acc1 = {0.f,0.f,0.f,0.f};
#pragma unroll
        for (int s = 0; s < 8; ++s) {
            if (s == 7) asm volatile("s_waitcnt vmcnt(0)" ::: "memory");
            else        asm volatile("s_waitcnt vmcnt(3)" ::: "memory");
            __builtin_amdgcn_s_barrier();
            if (s < 6) stage6(agb, bgb, stgb, (s + 2) % 3, kg * 8 + s + 2, w4, l);
            const ushort* La = stgb + (s % 3) * 6144;
            const ushort* Lb = La + 2048;
            short8 b0  = *(const short8*)(Lb + (size_t)w4 * 512 + l * 8);
            short8 a00 = *(const short8*)(La + (size_t)l * 8);
            short8 a01 = *(const short8*)(La + 512 + (size_t)l * 8);
            acc0 = __builtin_amdgcn_mfma_f32_16x16x32_bf16(a00, b0, acc0, 0, 0, 0);
            acc1 = __builtin_amdgcn_mfma_f32_16x16x32_bf16(a01, b0, acc1, 0, 0, 0);
            short8 b1  = *(const short8*)(Lb + (size_t)(4 + w4) * 512 + l * 8);
            short8 a10 = *(const short8*)(La + 1024 + (size_t)l * 8);
            short8 a11 = *(const short8*)(La + 1536 + (size_t)l * 8);
            acc0 = __builtin_amdgcn_mfma_f32_16x16x32_bf16(a10, b1, acc0, 0, 0, 0);
            acc1 = __builtin_amdgcn_mfma_f32_16x16x32_bf16(a11, b1, acc1, 0, 0, 0);
        }

        // split-K reduce into qs (group1 adds bias, applies softmax scale)
        {
            const int c = l & 15, rg = l >> 4;
            const int n = w4 * 16 + c;
            if (kg == 0) {
#pragma unroll
                for (int mb = 0; mb < 2; ++mb) {
                    f32x4 acc = mb ? acc1 : acc0;
#pragma unroll
                    for (int rr = 0; rr < 4; ++rr)
                        qs[mb * 16 + rg * 4 + rr][n] = acc[rr];
                }
            }
            __syncthreads();
            if (kg == 1) {
                float bv = a.b_attn[h * 64 + n];
#pragma unroll
                for (int mb = 0; mb < 2; ++mb) {
                    f32x4 acc = mb ? acc1 : acc0;
#pragma unroll
                    for (int rr = 0; rr < 4; ++rr) {
                        int m = mb * 16 + rg * 4 + rr;
                        qs[m][n] = (qs[m][n] + acc[rr] + bv) * 0.125f;
                    }
                }
            }
            __syncthreads();
        }

        // causal attention, 4 query rows per wave
#pragma unroll
        for (int rr = 0; rr < 4; ++rr) {
            const int i  = w * 4 + rr;
            const int gq = half * 32 + i;
            float s = 0.f;
#pragma unroll
            for (int d = 0; d < 64; ++d)
                s = fmaf(qs[i][d], ck_s[l][d], s);
            bool valid = (l <= gq);
            s = valid ? s : -3.0e38f;
            float mx = s;
#pragma unroll
            for (int o = 32; o; o >>= 1) mx = fmaxf(mx, __shfl_xor(mx, o));
            float e = valid ? __expf(s - mx) : 0.f;
            float sum = e;
#pragma unroll
            for (int o = 32; o; o >>= 1) sum += __shfl_xor(sum, o);
            float p = e / sum;

            float a0 = 0.f, a1 = 0.f, a2 = 0.f, a3 = 0.f;
#pragma unroll
            for (int j = 0; j < 64; j += 4) {
                a0 = fmaf(__shfl(p, j + 0), cv_s[j + 0][l], a0);
                a1 = fmaf(__shfl(p, j + 1), cv_s[j + 1][l], a1);
                a2 = fmaf(__shfl(p, j + 2), cv_s[j + 2][l], a2);
                a3 = fmaf(__shfl(p, j + 3), cv_s[j + 3][l], a3);
            }
            float acc = (a0 + a1) + (a2 + a3);

            int mb2 = i >> 4, r15 = i & 15;
            int kb  = l >> 5, ke = l & 31;
            int l2  = ((ke >> 3) << 4) | r15;
            int j2  = ke & 7;
            size_t off = (size_t)mtA * 32768 + (size_t)h * 2048
                       + (size_t)(kb * 2 + mb2) * 512 + (size_t)l2 * 8 + j2;
            a.yp[off] = f2bf(acc);
        }
    }

    if (fused) cg::this_grid().sync();

    // ---------------- phase 2: out = y @ w_proj + b_proj (split-K over 8 waves)
    if (fused || mode == 2) {
        const int nt2 = ((bid & 7) << 1) | ((bid >> 3) & 1);
        const int mt2 = bid >> 4;
        const ushort* agb = a.yp + (size_t)mt2 * 32768;
        const ushort* bgb = a.wp + (size_t)nt2 * 65536;
        ushort* stgb = &stg[kg][0][0];
        stage6(agb, bgb, stgb, 0, kg * 8 + 0, w4, l);
        stage6(agb, bgb, stgb, 1, kg * 8 + 1, w4, l);

        f32x4 acc0 = {0.f,0.f,0.f,0.f}, acc1 = {0.f,0.f,0.f,0.f};
#pragma unroll
        for (int s = 0; s < 8; ++s) {
            if (s == 7) asm volatile("s_waitcnt vmcnt(0)" ::: "memory");
            else        asm volatile("s_waitcnt vmcnt(3)" ::: "memory");
            __builtin_amdgcn_s_barrier();
            if (s < 6) stage6(agb, bgb, stgb, (s + 2) % 3, kg * 8 + s + 2, w4, l);
            const ushort* La = stgb + (s % 3) * 6144;
            const ushort* Lb = La + 2048;
            short8 b0  = *(const short8*)(Lb + (size_t)w4 * 512 + l * 8);
            short8 a00 = *(const short8*)(La + (size_t)l * 8);
            short8 a01 = *(const short8*)(La + 512 + (size_t)l * 8);
            acc0 = __builtin_amdgcn_mfma_f32_16x16x32_bf16(a00, b0, acc0, 0, 0, 0);
            acc1 = __builtin_amdgcn_mfma_f32_16x16x32_bf16(a01, b0, acc1, 0, 0, 0);
            short8 b1  = *(const short8*)(Lb + (size_t)(4 + w4) * 512 + l * 8);
            short8 a10 = *(const short8*)(La + 1024 + (size_t)l * 8);
            short8 a11 = *(const short8*)(La + 1536 + (size_t)l * 8);
            acc0 = __builtin_amdgcn_mfma_f32_16x16x32_bf16(a10, b1, acc0, 0, 0, 0);
            acc1 = __builtin_amdgcn_mfma_f32_16x16x32_bf16(a11, b1, acc1, 0, 0, 0);
        }

        const int c = l & 15, rg = l >> 4;
        const int nl = w4 * 16 + c;
        if (kg == 0) {
#pragma unroll
            for (int mb = 0; mb < 2; ++mb) {
                f32x4 acc = mb ? acc1 : acc0;
#pragma unroll
                for (int rr = 0; rr < 4; ++rr)
                    qs[mb * 16 + rg * 4 + rr][nl] = acc[rr];
            }
        }
        __syncthreads();
        if (kg == 1) {
            float bv = a.b_proj[nt2 * 64 + nl];
#pragma unroll
            for (int mb = 0; mb < 2; ++mb) {
                f32x4 acc = mb ? acc1 : acc0;
#pragma unroll
                for (int rr = 0; rr < 4; ++rr) {
                    int m = mb * 16 + rg * 4 + rr;
                    a.out[(size_t)(mt2 * 32 + m) * 1024 + nt2 * 64 + nl] =
                        qs[m][nl] + acc[rr] + bv;
                }
            }
        }
    }
}

// ---------------------------------------------------------------------------
extern "C" void kernel_launch(void* const* d_in, const int* in_sizes, int n_in,
                              void* d_out, int out_size, void* d_ws, size_t ws_size,
                              hipStream_t stream)
{
    MegaArgs a;
    a.x        = (const float*)d_in[0];
    a.cached_k = (const float*)d_in[1];
    a.cached_v = (const float*)d_in[2];
    a.w_attn   = (const float*)d_in[3];
    a.b_attn   = (const float*)d_in[4];
    a.w_proj   = (const float*)d_in[5];
    a.b_proj   = (const float*)d_in[6];
    a.kcw      = (const float*)d_in[7];
    a.vcw      = (const float*)d_in[8];
    a.lkg      = (const float*)d_in[9];
    a.lkb      = (const float*)d_in[10];
    a.lvg      = (const float*)d_in[11];
    a.lvb      = (const float*)d_in[12];

    ushort* xp = (ushort*)d_ws;
    a.xp = xp;                       // 524288 u16
    a.wq = xp + 524288;              // 1048576 u16
    a.wp = a.wq + 1048576;           // 1048576 u16
    a.yp = a.wp + 1048576;           // 524288 u16
    a.out = (float*)d_out;

    int mode = -1;
    void* kargs[2] = { (void*)&a, (void*)&mode };
    hipError_t err = hipLaunchCooperativeKernel((const void*)mega_kernel,
                                                dim3(256), dim3(512), kargs, 0, stream);
    if (err != hipSuccess) {
        // fallback: same kernel, three phase-launches (no grid sync needed)
        mega_kernel<<<256, 512, 0, stream>>>(a, 0);
        mega_kernel<<<256, 512, 0, stream>>>(a, 1);
        mega_kernel<<<256, 512, 0, stream>>>(a, 2);
    }
}

// Round 5
// 37.729 us; speedup vs baseline: 2.7737x; 2.7737x over previous
//
#include <hip/hip_runtime.h>
#include <math.h>

#define NH 16
#define LCACHE 4096

typedef __attribute__((ext_vector_type(8))) short short8;
typedef __attribute__((ext_vector_type(8))) unsigned short ushort8;
typedef __attribute__((ext_vector_type(4))) float f32x4;

__device__ __forceinline__ unsigned short f2bf(float f) {
    unsigned int u = __float_as_uint(f);
    u = (u + 0x7fffu + ((u >> 16) & 1u)) >> 16;   // RNE
    return (unsigned short)u;
}
__device__ __forceinline__ void gload16(const ushort* g, ushort* l) {
    __builtin_amdgcn_global_load_lds((const __attribute__((address_space(1))) void*)g,
                                     (__attribute__((address_space(3))) void*)l, 16, 0, 0);
}

// stage one K-tile (A 4 frags + B 8 frags) into 3-buffer ring
__device__ __forceinline__ void stage6(const ushort* agb, const ushort* bgb,
                                       ushort* stgb, int buf, int kt, int w4, int l)
{
    const ushort* ga = agb + (size_t)kt * 2048 + w4 * 512 + l * 8;
    const ushort* gb = bgb + (size_t)kt * 4096 + w4 * 1024 + l * 8;
    ushort* la = stgb + buf * 6144 + w4 * 512;
    ushort* lb = stgb + buf * 6144 + 2048 + w4 * 1024;
    gload16(ga, la); gload16(gb, lb); gload16(gb + 512, lb + 512);
}

// ---------------------------------------------------------------------------
// K1 prep: block-range specialized.
//  [0,256):   compress — one (b,h) & one tensor (K or V) per block; each of
//             the 64 visible rows computed ONCE; conv(s4,k4)+LN -> ck/cv (f32)
//  [256,512): pack w_attn[:, :1024] -> wq frags (LDS-staged coalesced reads)
//  [512,768): pack w_proj -> wp frags
//  [768,832): pack x -> xp A-frags
// Fragment-linear layout (1 KiB/frag), same bijection as rounds 2-4.
// ---------------------------------------------------------------------------
__global__ __launch_bounds__(256)
void prep_kernel(const float* __restrict__ cached_k, const float* __restrict__ cached_v,
                 const float* __restrict__ kcw, const float* __restrict__ vcw,
                 const float* __restrict__ lkg, const float* __restrict__ lkb,
                 const float* __restrict__ lvg, const float* __restrict__ lvb,
                 const float* __restrict__ x, const float* __restrict__ w_attn,
                 const float* __restrict__ w_proj,
                 float* __restrict__ ck, float* __restrict__ cv,
                 ushort* __restrict__ xp, ushort* __restrict__ wq,
                 ushort* __restrict__ wp)
{
    __shared__ float Wt[64][65];
    const int bid = blockIdx.x, tid = threadIdx.x;
    const int w = tid >> 6, l = tid & 63;

    if (bid < 256) {
        // ---- compress ----
        const int bh = bid >> 1, T = bid & 1;
        const float* S = (T ? cached_v : cached_k) + (size_t)bh * (LCACHE * 64);
        const float* cwp = T ? vcw : kcw;
        float4 w4 = *(const float4*)(cwp + l * 4);
        float g = (T ? lvg : lkg)[l], bb = (T ? lvb : lkb)[l];
        float* dst = (T ? cv : ck) + (size_t)bh * 4096;
#pragma unroll
        for (int it = 0; it < 4; ++it) {
            float av[4];
#pragma unroll
            for (int q = 0; q < 4; ++q) {
                int lc = w * 16 + it * 4 + q;
                const float* p = S + (size_t)lc * 256 + l;
                float acc = p[0] * w4.x;
                acc = fmaf(p[64],  w4.y, acc);
                acc = fmaf(p[128], w4.z, acc);
                acc = fmaf(p[192], w4.w, acc);
                av[q] = acc;
            }
            float s1[4], s2[4];
#pragma unroll
            for (int q = 0; q < 4; ++q) { s1[q] = av[q]; s2[q] = av[q] * av[q]; }
#pragma unroll
            for (int o = 32; o; o >>= 1) {
#pragma unroll
                for (int q = 0; q < 4; ++q) {
                    s1[q] += __shfl_xor(s1[q], o);
                    s2[q] += __shfl_xor(s2[q], o);
                }
            }
#pragma unroll
            for (int q = 0; q < 4; ++q) {
                int lc = w * 16 + it * 4 + q;
                float mu  = s1[q] * 0.015625f;
                float var = s2[q] * 0.015625f - mu * mu;
                dst[(size_t)lc * 64 + l] = (av[q] - mu) * rsqrtf(var + 1e-5f) * g + bb;
            }
        }
        return;
    }

    if (bid < 768) {
        // ---- W pack via LDS staging (coalesced 256B row reads) ----
        const int isP = (bid >= 512);
        const int g2  = bid - (isP ? 512 : 256);
        const int nt = g2 >> 4, kt = g2 & 15;
        const float* W = isP ? w_proj : w_attn;
        const int ldw  = isP ? 1024 : 3072;
        ushort* D      = isP ? wp : wq;
#pragma unroll
        for (int rep = 0; rep < 16; ++rep) {
            int lin = rep * 256 + tid;
            int kr = lin >> 6, nn = lin & 63;
            Wt[kr][nn] = W[(size_t)(kt * 64 + kr) * ldw + nt * 64 + nn];
        }
        __syncthreads();
        int r = l & 15, kg8 = l >> 4;
#pragma unroll
        for (int e = 0; e < 2; ++e) {
            int bi = w + e * 4;                   // 0..7
            int kb = bi >> 2, nb = bi & 3;
            ushort8 o;
#pragma unroll
            for (int j = 0; j < 8; ++j)
                o[j] = f2bf(Wt[kb * 32 + kg8 * 8 + j][nb * 16 + r]);
            size_t f_lin = (size_t)(nt * 16 + kt) * 8 + bi;
            *(ushort8*)(D + f_lin * 512 + l * 8) = o;
        }
        return;
    }

    // ---- x pack (direct; 128B-contiguous per row group) ----
    {
        int bid2 = bid - 768;                     // 0..63
        int r = l & 15, kg8 = l >> 4;
#pragma unroll
        for (int i = 0; i < 4; ++i) {
            int f = bid2 * 16 + w * 4 + i;        // 0..1023
            int mt = f >> 6, kt = (f >> 2) & 15, fi = f & 3;
            int kb = fi >> 1, mb = fi & 1;
            int m  = mt * 32 + mb * 16 + r;
            int k0 = kt * 64 + kb * 32 + kg8 * 8;
            const float* s = x + (size_t)m * 1024 + k0;
            ushort8 o;
#pragma unroll
            for (int j = 0; j < 8; ++j) o[j] = f2bf(s[j]);
            *(ushort8*)(xp + (size_t)f * 512 + l * 8) = o;
        }
    }
}

// ---------------------------------------------------------------------------
// K2: per (b,h,half).  ck/cv reg-prefetch (lands under the GEMM pipeline) |
// qgemm 32x64 split-K 3-buf counted-vmcnt pipeline | causal attention |
// yp write in packed-A layout.  256 blocks x 512 thr, XCD-swizzled h.
// ---------------------------------------------------------------------------
__global__ __launch_bounds__(512)
void attn_kernel(const float* __restrict__ ck, const float* __restrict__ cv,
                 const float* __restrict__ b_attn,
                 const ushort* __restrict__ xp, const ushort* __restrict__ wq,
                 ushort* __restrict__ yp)
{
    __shared__ __align__(16) ushort stg[2][3][6144];
    __shared__ float ck_s[64][65];
    __shared__ float cv_s[64][65];
    __shared__ float qs[32][68];

    const int bid = blockIdx.x;
    const int h    = ((bid & 7) << 1) | ((bid >> 3) & 1);   // same h -> same XCD
    const int rem  = bid >> 4;
    const int b    = rem >> 1;
    const int half = rem & 1;
    const int mtA  = b * 2 + half;

    const int tid = threadIdx.x;
    const int w = tid >> 6, l = tid & 63;
    const int kg = w >> 2, w4 = w & 3;

    // reg-prefetch ck/cv (oldest vm ops; drained by first counted wait)
    const float4* ckg = (const float4*)(ck + (size_t)(b * NH + h) * 4096);
    const float4* cvg = (const float4*)(cv + (size_t)(b * NH + h) * 4096);
    float4 rk0 = ckg[tid], rk1 = ckg[tid + 512];
    float4 rv0 = cvg[tid], rv1 = cvg[tid + 512];

    const ushort* agb = xp + (size_t)mtA * 32768;
    const ushort* bgb = wq + (size_t)h * 65536;
    ushort* stgb = &stg[kg][0][0];
    stage6(agb, bgb, stgb, 0, kg * 8 + 0, w4, l);
    stage6(agb, bgb, stgb, 1, kg * 8 + 1, w4, l);

    f32x4 acc0 = {0.f,0.f,0.f,0.f}, acc1 = {0.f,0.f,0.f,0.f};
#pragma unroll
    for (int s = 0; s < 8; ++s) {
        if (s == 7) asm volatile("s_waitcnt vmcnt(0)" ::: "memory");
        else        asm volatile("s_waitcnt vmcnt(3)" ::: "memory");
        __builtin_amdgcn_s_barrier();
        if (s < 6) stage6(agb, bgb, stgb, (s + 2) % 3, kg * 8 + s + 2, w4, l);
        const ushort* La = stgb + (s % 3) * 6144;
        const ushort* Lb = La + 2048;
        short8 b0  = *(const short8*)(Lb + (size_t)w4 * 512 + l * 8);
        short8 a00 = *(const short8*)(La + (size_t)l * 8);
        short8 a01 = *(const short8*)(La + 512 + (size_t)l * 8);
        acc0 = __builtin_amdgcn_mfma_f32_16x16x32_bf16(a00, b0, acc0, 0, 0, 0);
        acc1 = __builtin_amdgcn_mfma_f32_16x16x32_bf16(a01, b0, acc1, 0, 0, 0);
        short8 b1  = *(const short8*)(Lb + (size_t)(4 + w4) * 512 + l * 8);
        short8 a10 = *(const short8*)(La + 1024 + (size_t)l * 8);
        short8 a11 = *(const short8*)(La + 1536 + (size_t)l * 8);
        acc0 = __builtin_amdgcn_mfma_f32_16x16x32_bf16(a10, b1, acc0, 0, 0, 0);
        acc1 = __builtin_amdgcn_mfma_f32_16x16x32_bf16(a11, b1, acc1, 0, 0, 0);
    }

    // write prefetched ck/cv to LDS (scalar stores; pad-65 keeps reads 2-way free)
    {
        int row = tid >> 4, col = (tid & 15) * 4;
        ck_s[row][col] = rk0.x; ck_s[row][col+1] = rk0.y;
        ck_s[row][col+2] = rk0.z; ck_s[row][col+3] = rk0.w;
        ck_s[row+32][col] = rk1.x; ck_s[row+32][col+1] = rk1.y;
        ck_s[row+32][col+2] = rk1.z; ck_s[row+32][col+3] = rk1.w;
        cv_s[row][col] = rv0.x; cv_s[row][col+1] = rv0.y;
        cv_s[row][col+2] = rv0.z; cv_s[row][col+3] = rv0.w;
        cv_s[row+32][col] = rv1.x; cv_s[row+32][col+1] = rv1.y;
        cv_s[row+32][col+2] = rv1.z; cv_s[row+32][col+3] = rv1.w;
    }

    // split-K reduce into qs (group1 adds bias + softmax scale)
    {
        const int c = l & 15, rg = l >> 4;
        const int n = w4 * 16 + c;
        if (kg == 0) {
#pragma unroll
            for (int mb = 0; mb < 2; ++mb) {
                f32x4 acc = mb ? acc1 : acc0;
#pragma unroll
                for (int rr = 0; rr < 4; ++rr)
                    qs[mb * 16 + rg * 4 + rr][n] = acc[rr];
            }
        }
        __syncthreads();
        if (kg == 1) {
            float bv = b_attn[h * 64 + n];
#pragma unroll
            for (int mb = 0; mb < 2; ++mb) {
                f32x4 acc = mb ? acc1 : acc0;
#pragma unroll
                for (int rr = 0; rr < 4; ++rr) {
                    int m = mb * 16 + rg * 4 + rr;
                    qs[m][n] = (qs[m][n] + acc[rr] + bv) * 0.125f;
                }
            }
        }
        __syncthreads();
    }

    // causal attention, 4 query rows per wave
#pragma unroll
    for (int rr = 0; rr < 4; ++rr) {
        const int i  = w * 4 + rr;
        const int gq = half * 32 + i;
        float s = 0.f;
#pragma unroll
        for (int d = 0; d < 64; ++d)
            s = fmaf(qs[i][d], ck_s[l][d], s);
        bool valid = (l <= gq);
        s = valid ? s : -3.0e38f;
        float mx = s;
#pragma unroll
        for (int o = 32; o; o >>= 1) mx = fmaxf(mx, __shfl_xor(mx, o));
        float e = valid ? __expf(s - mx) : 0.f;
        float sum = e;
#pragma unroll
        for (int o = 32; o; o >>= 1) sum += __shfl_xor(sum, o);
        float p = e / sum;

        float a0 = 0.f, a1 = 0.f, a2 = 0.f, a3 = 0.f;
#pragma unroll
        for (int j = 0; j < 64; j += 4) {
            a0 = fmaf(__shfl(p, j + 0), cv_s[j + 0][l], a0);
            a1 = fmaf(__shfl(p, j + 1), cv_s[j + 1][l], a1);
            a2 = fmaf(__shfl(p, j + 2), cv_s[j + 2][l], a2);
            a3 = fmaf(__shfl(p, j + 3), cv_s[j + 3][l], a3);
        }
        float acc = (a0 + a1) + (a2 + a3);

        int mb2 = i >> 4, r15 = i & 15;
        int kb  = l >> 5, ke = l & 31;
        int l2  = ((ke >> 3) << 4) | r15;
        int j2  = ke & 7;
        size_t off = (size_t)mtA * 32768 + (size_t)h * 2048
                   + (size_t)(kb * 2 + mb2) * 512 + (size_t)l2 * 8 + j2;
        yp[off] = f2bf(acc);
    }
}

// ---------------------------------------------------------------------------
// K3: out = y @ w_proj + b_proj.  32x64 tile, split-K over 8 waves (2 groups
// of 4), 3-buf counted-vmcnt pipeline, LDS reduce.  XCD-swizzled nt.
// ---------------------------------------------------------------------------
__global__ __launch_bounds__(512)
void gemm2_kernel(const ushort* __restrict__ Ap, const ushort* __restrict__ Bp,
                  const float* __restrict__ bias, float* __restrict__ C)
{
    __shared__ __align__(16) ushort stg[2][3][6144];
    __shared__ float red[32][68];

    const int bid = blockIdx.x;
    const int nt = ((bid & 7) << 1) | ((bid >> 3) & 1);   // same nt -> same XCD
    const int mt = bid >> 4;
    const int tid = threadIdx.x;
    const int w = tid >> 6, l = tid & 63;
    const int kg = w >> 2, w4 = w & 3;

    const ushort* agb = Ap + (size_t)mt * 32768;
    const ushort* bgb = Bp + (size_t)nt * 65536;
    ushort* stgb = &stg[kg][0][0];
    stage6(agb, bgb, stgb, 0, kg * 8 + 0, w4, l);
    stage6(agb, bgb, stgb, 1, kg * 8 + 1, w4, l);

    f32x4 acc0 = {0.f,0.f,0.f,0.f}, acc1 = {0.f,0.f,0.f,0.f};
#pragma unroll
    for (int s = 0; s < 8; ++s) {
        if (s == 7) asm volatile("s_waitcnt vmcnt(0)" ::: "memory");
        else        asm volatile("s_waitcnt vmcnt(3)" ::: "memory");
        __builtin_amdgcn_s_barrier();
        if (s < 6) stage6(agb, bgb, stgb, (s + 2) % 3, kg * 8 + s + 2, w4, l);
        const ushort* La = stgb + (s % 3) * 6144;
        const ushort* Lb = La + 2048;
        short8 b0  = *(const short8*)(Lb + (size_t)w4 * 512 + l * 8);
        short8 a00 = *(const short8*)(La + (size_t)l * 8);
        short8 a01 = *(const short8*)(La + 512 + (size_t)l * 8);
        acc0 = __builtin_amdgcn_mfma_f32_16x16x32_bf16(a00, b0, acc0, 0, 0, 0);
        acc1 = __builtin_amdgcn_mfma_f32_16x16x32_bf16(a01, b0, acc1, 0, 0, 0);
        short8 b1  = *(const short8*)(Lb + (size_t)(4 + w4) * 512 + l * 8);
        short8 a10 = *(const short8*)(La + 1024 + (size_t)l * 8);
        short8 a11 = *(const short8*)(La + 1536 + (size_t)l * 8);
        acc0 = __builtin_amdgcn_mfma_f32_16x16x32_bf16(a10, b1, acc0, 0, 0, 0);
        acc1 = __builtin_amdgcn_mfma_f32_16x16x32_bf16(a11, b1, acc1, 0, 0, 0);
    }

    const int c = l & 15, rg = l >> 4;
    const int nl = w4 * 16 + c;
    if (kg == 0) {
#pragma unroll
        for (int mb = 0; mb < 2; ++mb) {
            f32x4 acc = mb ? acc1 : acc0;
#pragma unroll
            for (int rr = 0; rr < 4; ++rr)
                red[mb * 16 + rg * 4 + rr][nl] = acc[rr];
        }
    }
    __syncthreads();
    if (kg == 1) {
        float bv = bias[nt * 64 + nl];
#pragma unroll
        for (int mb = 0; mb < 2; ++mb) {
            f32x4 acc = mb ? acc1 : acc0;
#pragma unroll
            for (int rr = 0; rr < 4; ++rr) {
                int m = mb * 16 + rg * 4 + rr;
                C[(size_t)(mt * 32 + m) * 1024 + nt * 64 + nl] =
                    red[m][nl] + acc[rr] + bv;
            }
        }
    }
}

// ---------------------------------------------------------------------------
extern "C" void kernel_launch(void* const* d_in, const int* in_sizes, int n_in,
                              void* d_out, int out_size, void* d_ws, size_t ws_size,
                              hipStream_t stream)
{
    const float* x        = (const float*)d_in[0];
    const float* cached_k = (const float*)d_in[1];
    const float* cached_v = (const float*)d_in[2];
    const float* w_attn   = (const float*)d_in[3];
    const float* b_attn   = (const float*)d_in[4];
    const float* w_proj   = (const float*)d_in[5];
    const float* b_proj   = (const float*)d_in[6];
    const float* k_conv   = (const float*)d_in[7];
    const float* v_conv   = (const float*)d_in[8];
    const float* ln_k_g   = (const float*)d_in[9];
    const float* ln_k_b   = (const float*)d_in[10];
    const float* ln_v_g   = (const float*)d_in[11];
    const float* ln_v_b   = (const float*)d_in[12];

    ushort* xp = (ushort*)d_ws;            // 524288 u16
    ushort* wq = xp + 524288;              // 1048576 u16
    ushort* wp = wq + 1048576;             // 1048576 u16
    ushort* yp = wp + 1048576;             // 524288 u16
    float*  ck = (float*)(yp + 524288);    // 524288 f32
    float*  cv = ck + 524288;              // 524288 f32
    float*  out = (float*)d_out;

    prep_kernel<<<832, 256, 0, stream>>>(cached_k, cached_v, k_conv, v_conv,
                                         ln_k_g, ln_k_b, ln_v_g, ln_v_b,
                                         x, w_attn, w_proj, ck, cv, xp, wq, wp);
    attn_kernel<<<256, 512, 0, stream>>>(ck, cv, b_attn, xp, wq, yp);
    gemm2_kernel<<<256, 512, 0, stream>>>(yp, wp, b_proj, out);
}